// Round 9
// baseline (67.165 us; speedup 1.0000x reference)
//
#include <hip/hip_runtime.h>
#include <math.h>

// out[b,q] = T_q(xmean_b) * inner_sum[b,q]/IN
//   inner_sum[b,q] = sum_p c_q*sin(pi*(q+1)*x[b,p])*W[q,p]
//   xmean_b = (1/D) sum_q tanh(inner_sum[b,q]);  T_q(x)=cos(q*acos(x)), |xmean|<1
// theta input dead (corr == 0). sin in REVOLUTIONS: sin(pi*k*x) = v_sin((k/2)*x).
//
// R9: occupancy 4 -> 8 waves/SIMD. R3/R6/R8 (LDS ops 225/75/50 per wave) all pin at
// 14.8-15.0 us -> not LDS-issue-bound; invariants are trans+VALU count and 4 waves/SIMD
// with exposed in-order stalls. 512 blocks x 1024 thr = 2 blocks/CU = 32 waves/CU;
// two waves split each row's p-loop (13/12 iters), B-half parks partials in LDS,
// one barrier, A-half combines + epilogue. launch_bounds(1024,8) pins VGPR<=64.

#define IN_DIM 100
#define MAXD   100
#define NP4    (IN_DIM / 4)     // 25
#define WAVES  16
#define BLK    (WAVES * 64)     // 1024 threads
#define ROWS   8                // rows per block (2 waves per row)
#define SPLIT  13               // A-half: p4 in [0,13); B-half: [13,25)
#define INV2PI 0.15915494309189535f

__device__ __forceinline__ float fast_tanh(float v) {
    float e = __expf(2.0f * v);
    return 1.0f - 2.0f / (e + 1.0f);
}

__device__ __forceinline__ void inner_half(
    const float4* __restrict__ xb4,
    const float4 (* __restrict__ cwA)[64],
    const float4 (* __restrict__ cwB)[64],
    int lane, float f0, float f1, int p4_lo, int p4_hi,
    float& a0, float& a1)
{
    for (int p4 = p4_lo; p4 < p4_hi; ++p4) {
        float4 xv = xb4[p4];            // wave-uniform -> s_load (scalar broadcast)
        float4 c0 = cwA[p4][lane];      // lane-contiguous ds_read_b128
        float4 c1 = cwB[p4][lane];

        a0 = fmaf(__builtin_amdgcn_sinf(f0 * xv.x), c0.x, a0);
        a1 = fmaf(__builtin_amdgcn_sinf(f1 * xv.x), c1.x, a1);
        a0 = fmaf(__builtin_amdgcn_sinf(f0 * xv.y), c0.y, a0);
        a1 = fmaf(__builtin_amdgcn_sinf(f1 * xv.y), c1.y, a1);
        a0 = fmaf(__builtin_amdgcn_sinf(f0 * xv.z), c0.z, a0);
        a1 = fmaf(__builtin_amdgcn_sinf(f1 * xv.z), c1.z, a1);
        a0 = fmaf(__builtin_amdgcn_sinf(f0 * xv.w), c0.w, a0);
        a1 = fmaf(__builtin_amdgcn_sinf(f1 * xv.w), c1.w, a1);
    }
}

__global__ __launch_bounds__(BLK, 8) void kat_kernel(
    const float* __restrict__ x, const float* __restrict__ W,
    const int* __restrict__ dimp, float* __restrict__ out, int B)
{
    const int D = *dimp;
    const int P = (IN_DIM < D) ? IN_DIM : D;

    __shared__ float4 cwA[NP4][64];        // cq*W rows 0..63               (25.6 KB)
    __shared__ float4 cwB[NP4][64];        // cq*W rows 64..127 (zero >= D) (25.6 KB)
    __shared__ float2 part[ROWS][64];      // B-half partial sums           (4 KB)

    const int t = threadIdx.x;
    const int row0 = blockIdx.x * ROWS;

    // stage cwA/cwB = cq[q]*W[q][4p4..4p4+3]; q>=D or p>=P -> 0  (R6-proven)
    for (int idx = t; idx < NP4 * 128; idx += BLK) {
        int p4 = idx >> 7;
        int q  = idx & 127;
        float4 v = make_float4(0.f, 0.f, 0.f, 0.f);
        if (q < MAXD && q < D) {
            float k = (float)(q + 1);
            float c;
            if (q < 15) {
                c = 1.0f / k;
            } else {
                float qf = (float)q;
                float S = 1.0f + 0.2f * __logf(qf / 15.0f) * (1.0f - __expf(-0.03f * (qf - 15.0f)));
                c = 1.0f / (k * S);
            }
            c *= __expf(-0.03f * k * k);
            float4 wv = ((const float4*)W)[q * (MAXD / 4) + p4];
            int p = 4 * p4;
            v.x = (p     < P) ? c * wv.x : 0.0f;
            v.y = (p + 1 < P) ? c * wv.y : 0.0f;
            v.z = (p + 2 < P) ? c * wv.z : 0.0f;
            v.w = (p + 3 < P) ? c * wv.w : 0.0f;
        }
        if (q < 64) cwA[p4][q]      = v;
        else        cwB[p4][q - 64] = v;
    }
    __syncthreads();

    const int w    = t >> 6;
    const int lane = t & 63;
    const int pair = w & (ROWS - 1);   // which row of the block
    const int half = w >> 3;           // 0 = A (p4<13 + epilogue), 1 = B (p4>=13)
    const int b    = row0 + pair;

    // scalarize the (wave-uniform) row base so x loads hit the SMEM pipe
    const int bu = __builtin_amdgcn_readfirstlane((b < B) ? b : (B - 1));
    const float4* __restrict__ xb4 = (const float4*)(x + (size_t)bu * IN_DIM);

    const int q0 = lane;
    const int q1 = lane + 64;
    const float f0 = 0.5f * (float)(q0 + 1);  // revolutions
    const float f1 = 0.5f * (float)(q1 + 1);

    float a0 = 0.0f, a1 = 0.0f;
    if (half == 0) inner_half(xb4, cwA, cwB, lane, f0, f1, 0, SPLIT, a0, a1);
    else           inner_half(xb4, cwA, cwB, lane, f0, f1, SPLIT, NP4, a0, a1);

    if (half == 1) part[pair][lane] = make_float2(a0, a1);
    __syncthreads();

    if (half == 0) {
        float2 pb = part[pair][lane];
        a0 += pb.x;
        a1 += pb.y;

        // q>=D contributions staged as zero; tanh(0)=0
        float s = fast_tanh(a0) + fast_tanh(a1);
        #pragma unroll
        for (int m = 32; m; m >>= 1) s += __shfl_xor(s, m);

        const float thr = acosf(s / (float)D) * INV2PI;
        const float inv = 1.0f / (float)IN_DIM;
        if (b < B) {
            if (q0 < D) out[b * D + q0] = __builtin_amdgcn_cosf((float)q0 * thr) * a0 * inv;
            if (q1 < D) out[b * D + q1] = __builtin_amdgcn_cosf((float)q1 * thr) * a1 * inv;
        }
    }
}

extern "C" void kernel_launch(void* const* d_in, const int* in_sizes, int n_in,
                              void* d_out, int out_size, void* d_ws, size_t ws_size,
                              hipStream_t stream) {
    const float* x    = (const float*)d_in[0];
    const float* W    = (const float*)d_in[1];
    // d_in[2] = theta (unused: corr == 0)
    const int*   dimp = (const int*)d_in[3];
    float*       out  = (float*)d_out;

    const int B = in_sizes[0] / IN_DIM;          // 4096
    const int grid = (B + ROWS - 1) / ROWS;      // 512 blocks x 1024 threads = 2/CU

    hipLaunchKernelGGL(kat_kernel, dim3(grid), dim3(BLK), 0, stream,
                       x, W, dimp, out, B);
}

// Round 10
// 15.610 us; speedup vs baseline: 4.3028x; 4.3028x over previous
//
#include <hip/hip_runtime.h>
#include <math.h>

// out[b,q] = T_q(xmean_b) * inner_sum[b,q]/IN
//   inner_sum[b,q] = sum_p c_q*sin(pi*(q+1)*x[b,p])*W[q,p]
//   xmean_b = (1/D) sum_q tanh(inner_sum[b,q]);  T_q(x)=cos(q*acos(x)), |xmean|<1
// theta input dead (corr == 0). sin in REVOLUTIONS: sin(pi*k*x) = v_sin((k/2)*x).
//
// R10 = R9 p-split (2 waves per row -> 8192 waves -> 8 waves/SIMD possible) WITHOUT
// the forced min-waves bound. R7/R9 showed __launch_bounds__(,8) pins VGPR=32 and
// spills (87-130 MB scratch traffic) whenever the body needs more; R6 fit 32 by luck.
// Here: plain __launch_bounds__(1024); allocator free (~48-64 expected, no spill).
// 512 blocks x 1024 thr, LDS 55.3 KB -> 2 blocks/CU resident iff VGPR <= 64.

#define IN_DIM 100
#define MAXD   100
#define NP4    (IN_DIM / 4)     // 25
#define BLK    1024             // 16 waves
#define ROWS   8                // rows per block, 2 waves per row
#define SPLIT  13               // half A: p4 in [0,13); half B: [13,25)
#define INV2PI 0.15915494309189535f

__device__ __forceinline__ float fast_tanh(float v) {
    float e = __expf(2.0f * v);
    return 1.0f - 2.0f / (e + 1.0f);
}

__global__ __launch_bounds__(BLK) void kat_kernel(
    const float* __restrict__ x, const float* __restrict__ W,
    const int* __restrict__ dimp, float* __restrict__ out, int B)
{
    const int D = *dimp;
    const int P = (IN_DIM < D) ? IN_DIM : D;

    __shared__ float4 cwA[NP4][64];        // cq*W rows 0..63               (25.6 KB)
    __shared__ float4 cwB[NP4][64];        // cq*W rows 64..127 (zero >= D) (25.6 KB)
    __shared__ float2 part[ROWS][64];      // B-half partial sums           (4 KB)

    const int t = threadIdx.x;
    const int row0 = blockIdx.x * ROWS;

    // stage cwA/cwB = cq[q]*W[q][4p4..4p4+3]; q>=D or p>=P -> 0  (R6-proven)
    for (int idx = t; idx < NP4 * 128; idx += BLK) {
        int p4 = idx >> 7;
        int q  = idx & 127;
        float4 v = make_float4(0.f, 0.f, 0.f, 0.f);
        if (q < MAXD && q < D) {
            float k = (float)(q + 1);
            float c;
            if (q < 15) {
                c = 1.0f / k;
            } else {
                float qf = (float)q;
                float S = 1.0f + 0.2f * __logf(qf / 15.0f) * (1.0f - __expf(-0.03f * (qf - 15.0f)));
                c = 1.0f / (k * S);
            }
            c *= __expf(-0.03f * k * k);
            float4 wv = ((const float4*)W)[q * (MAXD / 4) + p4];
            int p = 4 * p4;
            v.x = (p     < P) ? c * wv.x : 0.0f;
            v.y = (p + 1 < P) ? c * wv.y : 0.0f;
            v.z = (p + 2 < P) ? c * wv.z : 0.0f;
            v.w = (p + 3 < P) ? c * wv.w : 0.0f;
        }
        if (q < 64) cwA[p4][q]      = v;
        else        cwB[p4][q - 64] = v;
    }
    __syncthreads();

    const int w    = t >> 6;
    const int lane = t & 63;
    const int pair = w & (ROWS - 1);   // row within block
    const int half = w >> 3;           // 0: p4<SPLIT + epilogue; 1: p4>=SPLIT
    const int b    = row0 + pair;

    // wave-uniform row base -> scalar (SMEM) x loads
    const int bu = __builtin_amdgcn_readfirstlane((b < B) ? b : (B - 1));
    const float4* __restrict__ xb4 = (const float4*)(x + (size_t)bu * IN_DIM);

    const int q0 = lane;
    const int q1 = lane + 64;
    const float f0 = 0.5f * (float)(q0 + 1);  // revolutions
    const float f1 = 0.5f * (float)(q1 + 1);

    const int p4_lo = half ? SPLIT : 0;
    const int p4_hi = half ? NP4   : SPLIT;

    float a0 = 0.0f, a1 = 0.0f;
    for (int p4 = p4_lo; p4 < p4_hi; ++p4) {
        float4 xv = xb4[p4];            // scalar broadcast load
        float4 c0 = cwA[p4][lane];      // lane-contiguous ds_read_b128
        float4 c1 = cwB[p4][lane];      // zero rows for q>=D

        a0 = fmaf(__builtin_amdgcn_sinf(f0 * xv.x), c0.x, a0);
        a1 = fmaf(__builtin_amdgcn_sinf(f1 * xv.x), c1.x, a1);
        a0 = fmaf(__builtin_amdgcn_sinf(f0 * xv.y), c0.y, a0);
        a1 = fmaf(__builtin_amdgcn_sinf(f1 * xv.y), c1.y, a1);
        a0 = fmaf(__builtin_amdgcn_sinf(f0 * xv.z), c0.z, a0);
        a1 = fmaf(__builtin_amdgcn_sinf(f1 * xv.z), c1.z, a1);
        a0 = fmaf(__builtin_amdgcn_sinf(f0 * xv.w), c0.w, a0);
        a1 = fmaf(__builtin_amdgcn_sinf(f1 * xv.w), c1.w, a1);
    }

    if (half == 1) part[pair][lane] = make_float2(a0, a1);
    __syncthreads();

    if (half == 0) {
        float2 pb = part[pair][lane];
        a0 += pb.x;
        a1 += pb.y;

        // q>=D contributions staged as zero; tanh(0)=0
        float s = fast_tanh(a0) + fast_tanh(a1);
        #pragma unroll
        for (int m = 32; m; m >>= 1) s += __shfl_xor(s, m);

        const float thr = acosf(s / (float)D) * INV2PI;
        const float inv = 1.0f / (float)IN_DIM;
        if (b < B) {
            if (q0 < D) out[b * D + q0] = __builtin_amdgcn_cosf((float)q0 * thr) * a0 * inv;
            if (q1 < D) out[b * D + q1] = __builtin_amdgcn_cosf((float)q1 * thr) * a1 * inv;
        }
    }
}

extern "C" void kernel_launch(void* const* d_in, const int* in_sizes, int n_in,
                              void* d_out, int out_size, void* d_ws, size_t ws_size,
                              hipStream_t stream) {
    const float* x    = (const float*)d_in[0];
    const float* W    = (const float*)d_in[1];
    // d_in[2] = theta (unused: corr == 0)
    const int*   dimp = (const int*)d_in[3];
    float*       out  = (float*)d_out;

    const int B = in_sizes[0] / IN_DIM;          // 4096
    const int grid = (B + ROWS - 1) / ROWS;      // 512 blocks x 1024 threads

    hipLaunchKernelGGL(kat_kernel, dim3(grid), dim3(BLK), 0, stream,
                       x, W, dimp, out, B);
}

// Round 11
// 14.765 us; speedup vs baseline: 4.5491x; 1.0572x over previous
//
#include <hip/hip_runtime.h>
#include <math.h>

// out[b,q] = T_q(xmean_b) * inner_sum[b,q]/IN
//   inner_sum[b,q] = sum_p c_q*sin(pi*(q+1)*x[b,p])*W[q,p]
//   xmean_b = (1/D) sum_q tanh(inner_sum[b,q]);  T_q(x)=cos(q*acos(x)), |xmean|<1
// theta input dead (corr == 0). sin in REVOLUTIONS: sin(pi*k*x) = v_sin((k/2)*x).
//
// R11: q-SPLIT for true 8 waves/SIMD. One wave per (row, q-half): half0 -> q in
// [0,64), half1 -> q in [64,100). No cross-wave work in the p-loop; only the
// tanh-sum crosses waves (1 float via LDS). Body is half of R6's (1 acc, 1 freq,
// ~20 VGPR) so the allocator stays under the 64-reg / 8-wave-per-SIMD cliff
// WITHOUT a min-waves bound (R7/R9 showed forced bounds spill; R10 showed a fat
// free body sits at >64 and falls back to 4/SIMD). 512 blocks x 1024 thr,
// LDS 51.3 KB -> 2 blocks/CU = 32 waves/CU = 8/SIMD.

#define IN_DIM 100
#define MAXD   100
#define NP4    (IN_DIM / 4)     // 25
#define BLK    1024             // 16 waves: 8 rows x 2 q-halves
#define ROWSB  8                // rows per block
#define INV2PI 0.15915494309189535f

__device__ __forceinline__ float fast_tanh(float v) {
    float e = __expf(2.0f * v);
    return 1.0f - 2.0f / (e + 1.0f);
}

__global__ __launch_bounds__(BLK) void kat_kernel(
    const float* __restrict__ x, const float* __restrict__ W,
    const int* __restrict__ dimp, float* __restrict__ out, int B)
{
    const int D = *dimp;
    const int P = (IN_DIM < D) ? IN_DIM : D;

    __shared__ float4 cw[NP4][128];        // cq*W, [p4][q], zero q>=D  (51.2 KB)
    __shared__ float  rowsum[ROWSB][2];    // per-row tanh partial sums

    const int t = threadIdx.x;
    const int row0 = blockIdx.x * ROWSB;

    // stage cw = cq[q]*W[q][4p4..4p4+3]; q>=D or p>=P -> 0  (R6-proven math)
    for (int idx = t; idx < NP4 * 128; idx += BLK) {
        int p4 = idx >> 7;
        int q  = idx & 127;
        float4 v = make_float4(0.f, 0.f, 0.f, 0.f);
        if (q < MAXD && q < D) {
            float k = (float)(q + 1);
            float c;
            if (q < 15) {
                c = 1.0f / k;
            } else {
                float qf = (float)q;
                float S = 1.0f + 0.2f * __logf(qf / 15.0f) * (1.0f - __expf(-0.03f * (qf - 15.0f)));
                c = 1.0f / (k * S);
            }
            c *= __expf(-0.03f * k * k);
            float4 wv = ((const float4*)W)[q * (MAXD / 4) + p4];
            int p = 4 * p4;
            v.x = (p     < P) ? c * wv.x : 0.0f;
            v.y = (p + 1 < P) ? c * wv.y : 0.0f;
            v.z = (p + 2 < P) ? c * wv.z : 0.0f;
            v.w = (p + 3 < P) ? c * wv.w : 0.0f;
        }
        cw[p4][q] = v;
    }
    __syncthreads();

    const int w    = t >> 6;
    const int lane = t & 63;
    const int r    = w & (ROWSB - 1);   // row within block
    const int half = w >> 3;            // 0: q<64, 1: q>=64
    const int b    = row0 + r;

    // wave-uniform row base -> scalar (SMEM) x loads
    const int bu = __builtin_amdgcn_readfirstlane((b < B) ? b : (B - 1));
    const float4* __restrict__ xb4 = (const float4*)(x + (size_t)bu * IN_DIM);

    const int   qi = lane + (half << 6);        // this lane's q
    const float f  = 0.5f * (float)(qi + 1);    // revolutions

    float a = 0.0f;
    for (int p4 = 0; p4 < NP4; ++p4) {
        float4 xv = xb4[p4];            // scalar broadcast load
        float4 c  = cw[p4][qi];         // lane-contiguous ds_read_b128

        a = fmaf(__builtin_amdgcn_sinf(f * xv.x), c.x, a);
        a = fmaf(__builtin_amdgcn_sinf(f * xv.y), c.y, a);
        a = fmaf(__builtin_amdgcn_sinf(f * xv.z), c.z, a);
        a = fmaf(__builtin_amdgcn_sinf(f * xv.w), c.w, a);
    }

    // per-wave tanh sum over its 64 q (q>=D staged zero -> tanh(0)=0)
    float s = fast_tanh(a);
    #pragma unroll
    for (int m = 32; m; m >>= 1) s += __shfl_xor(s, m);
    if (lane == 0) rowsum[r][half] = s;
    __syncthreads();

    const float tot = rowsum[r][0] + rowsum[r][1];
    const float thr = acosf(tot / (float)D) * INV2PI;
    const float inv = 1.0f / (float)IN_DIM;
    if (b < B && qi < D)
        out[b * D + qi] = __builtin_amdgcn_cosf((float)qi * thr) * a * inv;
}

extern "C" void kernel_launch(void* const* d_in, const int* in_sizes, int n_in,
                              void* d_out, int out_size, void* d_ws, size_t ws_size,
                              hipStream_t stream) {
    const float* x    = (const float*)d_in[0];
    const float* W    = (const float*)d_in[1];
    // d_in[2] = theta (unused: corr == 0)
    const int*   dimp = (const int*)d_in[3];
    float*       out  = (float*)d_out;

    const int B = in_sizes[0] / IN_DIM;          // 4096
    const int grid = (B + ROWSB - 1) / ROWSB;    // 512 blocks x 1024 threads

    hipLaunchKernelGGL(kat_kernel, dim3(grid), dim3(BLK), 0, stream,
                       x, W, dimp, out, B);
}